// Round 3
// baseline (931.579 us; speedup 1.0000x reference)
//
#include <hip/hip_runtime.h>
#include <hip/hip_bf16.h>

typedef unsigned short ushort;
typedef short bf16x8 __attribute__((ext_vector_type(8)));
typedef float f32x4 __attribute__((ext_vector_type(4)));

#define NB 8
#define SS 2048
#define DD 768
#define DKV 214
#define DKP 224

__device__ __forceinline__ float bf2f(ushort u) {
  union { unsigned int i; float f; } v; v.i = ((unsigned int)u) << 16; return v.f;
}
__device__ __forceinline__ ushort f2bf(float f) {
  union { float f; unsigned int i; } v; v.f = f;
  unsigned int x = v.i;
  return (ushort)((x + 0x7fffu + ((x >> 16) & 1u)) >> 16);
}
// convert 8 consecutive f32 (32B-aligned) to one bf16x8 fragment (RNE)
__device__ __forceinline__ bf16x8 cvt8(const float* p) {
  f32x4 a = *(const f32x4*)p;
  f32x4 b = *(const f32x4*)(p + 4);
  bf16x8 r;
#pragma unroll
  for (int j = 0; j < 4; ++j) { r[j] = (short)f2bf(a[j]); r[j + 4] = (short)f2bf(b[j]); }
  return r;
}
// split 8 f32 into hi/lo bf16 fragments: x ~= hi + lo  (error ~2^-17 rel)
__device__ __forceinline__ void split8(const float* p, bf16x8& h, bf16x8& l) {
  f32x4 a = *(const f32x4*)p;
  f32x4 b = *(const f32x4*)(p + 4);
#pragma unroll
  for (int j = 0; j < 4; ++j) {
    ushort h0 = f2bf(a[j]); h[j]     = (short)h0; l[j]     = (short)f2bf(a[j] - bf2f(h0));
    ushort h1 = f2bf(b[j]); h[j + 4] = (short)h1; l[j + 4] = (short)f2bf(b[j] - bf2f(h1));
  }
}

// C[m][n] = sum_d A[m][d]*Bw[n][d] + bias[n]   (A,Bw,bias f32)
// SPLIT_IN:  3-term split-bf16 MFMA (near-f32 precision); else single bf16.
// !TRANS_OUT: writes hi/lo bf16 pair (Ch, Cl), cols >= NVALID zeroed.
// TRANS_OUT:  writes Vt[b][n][s] single bf16 (V transposed per batch).
template<int NVALID, bool TRANS_OUT, bool SPLIT_IN>
__global__ __launch_bounds__(256)
void gemm_bt(const float* __restrict__ A, const float* __restrict__ Bw,
             const float* __restrict__ bias, ushort* __restrict__ Ch,
             ushort* __restrict__ Cl, int Nout)
{
  const int m0 = blockIdx.x * 64;
  const int n0 = blockIdx.y * 64;
  const int tid = threadIdx.x;
  const int w  = tid >> 6;
  const int l  = tid & 63;
  const int lr = l & 15;
  const int lh = l >> 4;

  const f32x4 fzero = {0.f, 0.f, 0.f, 0.f};
  const bf16x8 bzero = {0,0,0,0,0,0,0,0};
  f32x4 acc[4];
#pragma unroll
  for (int nt = 0; nt < 4; ++nt) acc[nt] = fzero;

  const float* arow = A + (size_t)(m0 + w * 16 + lr) * DD + lh * 8;
  int nidx[4]; bool nval[4];
  const float* brow[4];
#pragma unroll
  for (int nt = 0; nt < 4; ++nt) {
    nidx[nt] = n0 + nt * 16 + lr;
    nval[nt] = (nidx[nt] < NVALID);
    brow[nt] = Bw + (size_t)(nval[nt] ? nidx[nt] : 0) * DD + lh * 8;
  }

  for (int k = 0; k < DD; k += 32) {
    if constexpr (SPLIT_IN) {
      bf16x8 ah, al; split8(arow + k, ah, al);
#pragma unroll
      for (int nt = 0; nt < 4; ++nt) {
        bf16x8 bh = bzero, bl = bzero;
        if (nval[nt]) split8(brow[nt] + k, bh, bl);
        acc[nt] = __builtin_amdgcn_mfma_f32_16x16x32_bf16(ah, bh, acc[nt], 0, 0, 0);
        acc[nt] = __builtin_amdgcn_mfma_f32_16x16x32_bf16(ah, bl, acc[nt], 0, 0, 0);
        acc[nt] = __builtin_amdgcn_mfma_f32_16x16x32_bf16(al, bh, acc[nt], 0, 0, 0);
      }
    } else {
      bf16x8 af = cvt8(arow + k);
#pragma unroll
      for (int nt = 0; nt < 4; ++nt) {
        bf16x8 bfr = bzero;
        if (nval[nt]) bfr = cvt8(brow[nt] + k);
        acc[nt] = __builtin_amdgcn_mfma_f32_16x16x32_bf16(af, bfr, acc[nt], 0, 0, 0);
      }
    }
  }

  if constexpr (!TRANS_OUT) {
#pragma unroll
    for (int nt = 0; nt < 4; ++nt) {
      int n = nidx[nt];
      if (n >= Nout) continue;
      float bv = nval[nt] ? bias[n] : 0.f;
#pragma unroll
      for (int r = 0; r < 4; ++r) {
        int m = m0 + w * 16 + lh * 4 + r;
        float val = nval[nt] ? (acc[nt][r] + bv) : 0.f;
        ushort h = f2bf(val);
        Ch[(size_t)m * Nout + n] = h;
        Cl[(size_t)m * Nout + n] = f2bf(val - bf2f(h));
      }
    }
  } else {
    __shared__ ushort lt[64][72];
#pragma unroll
    for (int nt = 0; nt < 4; ++nt) {
      int nl = nt * 16 + lr;
      float bv = bias[n0 + nl];
#pragma unroll
      for (int r = 0; r < 4; ++r)
        lt[nl][w * 16 + lh * 4 + r] = f2bf(acc[nt][r] + bv);
    }
    __syncthreads();
    const int bb = m0 >> 11;
    const int s0 = m0 & 2047;
    for (int i = tid; i < 64 * 64; i += 256) {
      int nn = i >> 6, mm = i & 63;
      Ch[(size_t)bb * (DD * SS) + (size_t)(n0 + nn) * SS + (s0 + mm)] = lt[nn][mm];
    }
  }
}

// Fused attention: per block = one batch b, 32 q-rows. 8 waves (512 thr).
// Online softmax over t in tiles of 64. Wave w: S-quadrant rows (w&1)*16..+15,
// cols (w>>1)*16..+15; PV d-slice = w*96..+95 over all 32 rows.
// QK^T in split-bf16 (3 MFMAs per k-step) for near-f32 logits.
__global__ __launch_bounds__(512)
void attn_fused(const ushort* __restrict__ Qh, const ushort* __restrict__ Ql,
                const ushort* __restrict__ Kh, const ushort* __restrict__ Kl,
                const ushort* __restrict__ Vt, const float* __restrict__ isc,
                const float* __restrict__ dmask, float* __restrict__ out)
{
  const int bb = blockIdx.x >> 6;
  const int q0 = (blockIdx.x & 63) << 5;
  const int tid = threadIdx.x;
  const int w  = tid >> 6;
  const int l  = tid & 63;
  const int lr = l & 15;
  const int lh = l >> 4;
  const int rh = w & 1;    // row half of S quadrant
  const int cq = w >> 1;   // col quarter of S quadrant

  __shared__ __align__(16) ushort Qlh[32][232];    // hi, padded stride
  __shared__ __align__(16) ushort Qll[32][232];    // lo
  __shared__ __align__(16) ushort Plds[2048];      // [32][64] bf16, XOR-swizzled
  __shared__ float part_max[4][32];
  __shared__ float part_sum[4][32];
  __shared__ float alpha_l[32];
  __shared__ float rcpZ[32];

  {
    const size_t qoff = (size_t)(bb * SS + q0) * DKP;
    for (int i = tid; i < 32 * 28; i += 512) {
      int r = i / 28, c = i % 28;
      *(bf16x8*)(&Qlh[r][c * 8]) = *(const bf16x8*)(Qh + qoff + r * DKP + c * 8);
      *(bf16x8*)(&Qll[r][c * 8]) = *(const bf16x8*)(Ql + qoff + r * DKP + c * 8);
    }
  }
  __syncthreads();

  const f32x4 fzero = {0.f, 0.f, 0.f, 0.f};
  float m_run[4], Z_run[4];
#pragma unroll
  for (int r = 0; r < 4; ++r) { m_run[r] = -1e30f; Z_run[r] = 0.f; }
  f32x4 Oacc[2][6];
#pragma unroll
  for (int mt = 0; mt < 2; ++mt)
#pragma unroll
    for (int dt = 0; dt < 6; ++dt) Oacc[mt][dt] = fzero;

  const int qrow_w = rh * 16 + lh * 4;   // wave's S-rows base (block-local)

  for (int it = 0; it < SS / 64; ++it) {
    const int t0 = it * 64;
    // ---- S = Q K^T (split-bf16), one 16x16 per wave, 7 k-steps over 224 ----
    f32x4 sacc = fzero;
    const size_t koff = (size_t)(bb * SS + t0 + cq * 16 + lr) * DKP + lh * 8;
    const ushort* krh = Kh + koff;
    const ushort* krl = Kl + koff;
#pragma unroll
    for (int k = 0; k < 7; ++k) {
      bf16x8 ah = *(const bf16x8*)(&Qlh[rh * 16 + lr][k * 32 + lh * 8]);
      bf16x8 al = *(const bf16x8*)(&Qll[rh * 16 + lr][k * 32 + lh * 8]);
      bf16x8 bh = *(const bf16x8*)(krh + k * 32);
      bf16x8 bl = *(const bf16x8*)(krl + k * 32);
      sacc = __builtin_amdgcn_mfma_f32_16x16x32_bf16(ah, bh, sacc, 0, 0, 0);
      sacc = __builtin_amdgcn_mfma_f32_16x16x32_bf16(ah, bl, sacc, 0, 0, 0);
      sacc = __builtin_amdgcn_mfma_f32_16x16x32_bf16(al, bh, sacc, 0, 0, 0);
    }
    // elementwise divide by inv_scale[s][t] (f32)
    const int tcol = t0 + cq * 16 + lr;
    float sv[4];
#pragma unroll
    for (int r = 0; r < 4; ++r) {
      float iv = isc[(size_t)(q0 + qrow_w + r) * SS + tcol];
      sv[r] = sacc[r] * __builtin_amdgcn_rcpf(iv);
    }
    // per-row max across the 16 lanes of this lane-group
    float mx[4];
#pragma unroll
    for (int r = 0; r < 4; ++r) mx[r] = sv[r];
#pragma unroll
    for (int off = 1; off < 16; off <<= 1) {
#pragma unroll
      for (int r = 0; r < 4; ++r) mx[r] = fmaxf(mx[r], __shfl_xor(mx[r], off));
    }
    if (lr == 0) {
#pragma unroll
      for (int r = 0; r < 4; ++r) part_max[cq][qrow_w + r] = mx[r];
    }
    __syncthreads();
    // combine col-quarters, online update, exp
    float alpha[4], e[4], zl[4];
#pragma unroll
    for (int r = 0; r < 4; ++r) {
      int row = qrow_w + r;
      float mt4 = fmaxf(fmaxf(part_max[0][row], part_max[1][row]),
                        fmaxf(part_max[2][row], part_max[3][row]));
      float mnew = fmaxf(m_run[r], mt4);
      alpha[r] = __expf(m_run[r] - mnew);
      m_run[r] = mnew;
      e[r]  = __expf(sv[r] - mnew);
      zl[r] = e[r];
    }
#pragma unroll
    for (int off = 1; off < 16; off <<= 1) {
#pragma unroll
      for (int r = 0; r < 4; ++r) zl[r] += __shfl_xor(zl[r], off);
    }
    if (lr == 0) {
#pragma unroll
      for (int r = 0; r < 4; ++r) part_sum[cq][qrow_w + r] = zl[r];
      if (cq == 0) {
#pragma unroll
        for (int r = 0; r < 4; ++r) alpha_l[qrow_w + r] = alpha[r];
      }
    }
    // P = e * dropout_mask (mask applied AFTER normalization in ref; Z unmasked)
#pragma unroll
    for (int r = 0; r < 4; ++r) {
      int row = qrow_w + r;
      int col = cq * 16 + lr;
      float mk = dmask[(size_t)bb * SS * SS + (size_t)(q0 + row) * SS + (t0 + col)];
      unsigned off = (unsigned)(row * 128 + col * 2) ^ (((unsigned)row & 7u) << 4);
      *(ushort*)((char*)Plds + off) = f2bf(e[r] * mk);
    }
    __syncthreads();
    // Z update (own rows, all four col-quarters)
#pragma unroll
    for (int r = 0; r < 4; ++r) {
      int row = qrow_w + r;
      Z_run[r] = Z_run[r] * alpha[r] +
                 part_sum[0][row] + part_sum[1][row] + part_sum[2][row] + part_sum[3][row];
    }
    // O rescale (skip when no row max moved)
    float oal[2][4]; int need = 0;
#pragma unroll
    for (int mt = 0; mt < 2; ++mt) {
#pragma unroll
      for (int r = 0; r < 4; ++r) {
        float a = alpha_l[mt * 16 + lh * 4 + r];
        oal[mt][r] = a;
        need |= (a != 1.f);
      }
    }
    if (__any(need)) {
#pragma unroll
      for (int mt = 0; mt < 2; ++mt)
#pragma unroll
        for (int dt = 0; dt < 6; ++dt)
#pragma unroll
          for (int r = 0; r < 4; ++r) Oacc[mt][dt][r] *= oal[mt][r];
    }
    // PV: A-frags from swizzled Plds, B-frags from Vt (row-major over t)
    bf16x8 pf[2][2];
#pragma unroll
    for (int mt = 0; mt < 2; ++mt) {
#pragma unroll
      for (int ks = 0; ks < 2; ++ks) {
        int row = mt * 16 + lr;
        unsigned off = (unsigned)(row * 128 + ks * 64 + lh * 16) ^ (((unsigned)row & 7u) << 4);
        pf[mt][ks] = *(const bf16x8*)((char*)Plds + off);
      }
    }
    const ushort* vbase = Vt + (size_t)bb * (DD * SS) + (size_t)(w * 96 + lr) * SS + t0 + lh * 8;
#pragma unroll
    for (int dt = 0; dt < 6; ++dt) {
#pragma unroll
      for (int ks = 0; ks < 2; ++ks) {
        bf16x8 vf = *(const bf16x8*)(vbase + (size_t)dt * 16 * SS + ks * 32);
        Oacc[0][dt] = __builtin_amdgcn_mfma_f32_16x16x32_bf16(pf[0][ks], vf, Oacc[0][dt], 0, 0, 0);
        Oacc[1][dt] = __builtin_amdgcn_mfma_f32_16x16x32_bf16(pf[1][ks], vf, Oacc[1][dt], 0, 0, 0);
      }
    }
    __syncthreads();
  }

  if (w < 2 && lr == 0) {
#pragma unroll
    for (int r = 0; r < 4; ++r) rcpZ[qrow_w + r] = 1.0f / Z_run[r];
  }
  __syncthreads();

  float* obase = out + (size_t)(bb * SS + q0) * DD + w * 96;
#pragma unroll
  for (int mt = 0; mt < 2; ++mt) {
#pragma unroll
    for (int dt = 0; dt < 6; ++dt) {
#pragma unroll
      for (int r = 0; r < 4; ++r) {
        int row = mt * 16 + lh * 4 + r;
        obase[(size_t)row * DD + dt * 16 + lr] = Oacc[mt][dt][r] * rcpZ[row];
      }
    }
  }
}

extern "C" void kernel_launch(void* const* d_in, const int* in_sizes, int n_in,
                              void* d_out, int out_size, void* d_ws, size_t ws_size,
                              hipStream_t stream) {
  const float* x1  = (const float*)d_in[0];
  const float* x2  = (const float*)d_in[1];
  const float* x3  = (const float*)d_in[2];
  const float* Wq  = (const float*)d_in[3];
  const float* bq  = (const float*)d_in[4];
  const float* Wk  = (const float*)d_in[5];
  const float* bk  = (const float*)d_in[6];
  const float* Wv  = (const float*)d_in[7];
  const float* bv  = (const float*)d_in[8];
  const float* isc = (const float*)d_in[9];
  const float* dmk = (const float*)d_in[10];
  float* out = (float*)d_out;

  const size_t QK = (size_t)16384 * DKP;          // 3.67M elems
  ushort* Qh = (ushort*)d_ws;                     // [16384][224] bf16 hi
  ushort* Ql = Qh + QK;                           // lo
  ushort* Kh = Ql + QK;
  ushort* Kl = Kh + QK;
  ushort* Vt = Kl + QK;                           // [8][768][2048] bf16

  dim3 blk(256);
  gemm_bt<DKV, false, true ><<<dim3(256, 4),  blk, 0, stream>>>(x1, Wq, bq, Qh, Ql, DKP);
  gemm_bt<DKV, false, true ><<<dim3(256, 4),  blk, 0, stream>>>(x2, Wk, bk, Kh, Kl, DKP);
  gemm_bt<DD,  true,  false><<<dim3(256, 12), blk, 0, stream>>>(x3, Wv, bv, Vt, nullptr, 0);
  attn_fused<<<dim3(512), dim3(512), 0, stream>>>(Qh, Ql, Kh, Kl, Vt, isc, dmk, out);
}